// Round 2
// baseline (191.510 us; speedup 1.0000x reference)
//
#include <hip/hip_runtime.h>
#include <math.h>

#define HIDDEN  512
#define EXPERTS 4

// Quad-transpose + butterfly reduction: input s0..s3 = this lane's partial
// sums for experts 0..3. Output L0..L3 = full 64-lane dot sums for experts
// 0..3, identical in every lane. 10 shuffle ops, ~7 dependent hops.
__device__ __forceinline__ void reduce4(float s0, float s1, float s2, float s3,
                                        int b0, int b1,
                                        float& L0, float& L1, float& L2, float& L3)
{
    // step 1 (xor 1): lane keeps experts {2*b0, 2*b0+1}, gives away the rest
    float y0 = b0 ? s0 : s2;
    float y1 = b0 ? s1 : s3;
    float r0 = __shfl_xor(y0, 1, 64);
    float r1 = __shfl_xor(y1, 1, 64);
    float u0 = (b0 ? s2 : s0) + r0;   // expert 2*b0   summed over lane pair
    float u1 = (b0 ? s3 : s1) + r1;   // expert 2*b0+1 summed over lane pair
    // step 2 (xor 2): lane keeps expert 2*b0 + b1
    float y2 = b1 ? u0 : u1;
    float r2 = __shfl_xor(y2, 2, 64);
    float v  = (b1 ? u1 : u0) + r2;   // expert (2*b0+b1) summed over quad
    // butterfly over remaining lanes
    v += __shfl_xor(v, 4, 64);
    v += __shfl_xor(v, 8, 64);
    v += __shfl_xor(v, 16, 64);
    v += __shfl_xor(v, 32, 64);
    // gather: each lane collects all 4 experts from its quad
    float g1 = __shfl_xor(v, 1, 64);  // expert 2*(1-b0) + b1
    float g2 = __shfl_xor(v, 2, 64);  // expert 2*b0 + (1-b1)
    float g3 = __shfl_xor(v, 3, 64);  // expert 2*(1-b0) + (1-b1)
    L0 = b1 ? (b0 ? g3 : g2) : (b0 ? g1 : v);
    L1 = b1 ? (b0 ? g1 : v ) : (b0 ? g3 : g2);
    L2 = b1 ? (b0 ? g2 : g3) : (b0 ? v  : g1);
    L3 = b1 ? (b0 ? v  : g1) : (b0 ? g2 : g3);
}

// One wave per 4 consecutive tokens. Lane l covers x positions {4l..4l+3} and
// {256+4l..256+4l+3} of each row. 4 independent reduction chains per
// iteration hide shuffle/load latency.
__global__ __launch_bounds__(256, 4) void gating_kernel(
    const float* __restrict__ x,        // [T, 512]
    const float* __restrict__ gate_w,   // [4, 512]
    const float* __restrict__ gate_b,   // [4]
    float* __restrict__ out_sparse,     // [T, 4]
    float* __restrict__ out_idx,        // [T, 2] (indices stored as float)
    float* __restrict__ out_logit,     // [T, 4]
    int T)
{
    const int lane   = threadIdx.x & 63;
    const int wave   = (int)((blockIdx.x * blockDim.x + threadIdx.x) >> 6);
    const int nwaves = (int)((gridDim.x * blockDim.x) >> 6);
    const int b0 = lane & 1, b1 = (lane >> 1) & 1;

    // Gate fragments in registers: 4 experts x 8 floats = 32 VGPRs.
    float4 gw0[EXPERTS], gw1[EXPERTS];
#pragma unroll
    for (int e = 0; e < EXPERTS; ++e) {
        gw0[e] = *reinterpret_cast<const float4*>(gate_w + e * HIDDEN + lane * 4);
        gw1[e] = *reinterpret_cast<const float4*>(gate_w + e * HIDDEN + 256 + lane * 4);
    }
    const float bb0 = gate_b[0], bb1 = gate_b[1], bb2 = gate_b[2], bb3 = gate_b[3];

    for (int t4 = wave * 4; t4 + 3 < T; t4 += nwaves * 4) {
        // ---- load 4 consecutive token rows (8 KB contiguous per wave) ----
        float4 xa[4], xb[4];
#pragma unroll
        for (int i = 0; i < 4; ++i) {
            const float* xt = x + (size_t)(t4 + i) * HIDDEN;
            xa[i] = *reinterpret_cast<const float4*>(xt + lane * 4);
            xb[i] = *reinterpret_cast<const float4*>(xt + 256 + lane * 4);
        }

        // ---- partial dots: 4 tokens x 4 experts ----
        float L[4][EXPERTS];   // per-token logits (post-reduction)
#pragma unroll
        for (int i = 0; i < 4; ++i) {
            float s[EXPERTS];
#pragma unroll
            for (int e = 0; e < EXPERTS; ++e) {
                s[e] = xa[i].x * gw0[e].x + xa[i].y * gw0[e].y
                     + xa[i].z * gw0[e].z + xa[i].w * gw0[e].w
                     + xb[i].x * gw1[e].x + xb[i].y * gw1[e].y
                     + xb[i].z * gw1[e].z + xb[i].w * gw1[e].w;
            }
            reduce4(s[0], s[1], s[2], s[3], b0, b1,
                    L[i][0], L[i][1], L[i][2], L[i][3]);
        }

        // ---- topk + softmax (wave-uniform, all lanes compute) ----
        float sp[4][4], lv[4][4], iv0[4], iv1[4];
#pragma unroll
        for (int i = 0; i < 4; ++i) {
            const float l0 = L[i][0] + bb0, l1 = L[i][1] + bb1;
            const float l2 = L[i][2] + bb2, l3 = L[i][3] + bb3;
            const float l[4] = {l0, l1, l2, l3};
            int i1 = 0; float m1 = l[0];
#pragma unroll
            for (int e = 1; e < 4; ++e) { if (l[e] > m1) { m1 = l[e]; i1 = e; } }
            int i2 = -1; float m2 = -INFINITY;
#pragma unroll
            for (int e = 0; e < 4; ++e) { if (e != i1 && l[e] > m2) { m2 = l[e]; i2 = e; } }
            const float e2  = __expf(m2 - m1);
            const float inv = 1.0f / (1.0f + e2);
#pragma unroll
            for (int e = 0; e < 4; ++e)
                sp[i][e] = (e == i1) ? inv : ((e == i2) ? e2 * inv : 0.0f);
            lv[i][0] = l0; lv[i][1] = l1; lv[i][2] = l2; lv[i][3] = l3;
            iv0[i] = (float)i1; iv1[i] = (float)i2;
        }

        // ---- stores: lane 0 writes 4 tokens (contiguous regions) ----
        if (lane == 0) {
#pragma unroll
            for (int i = 0; i < 4; ++i) {
                const int t = t4 + i;
                float4 spv = {sp[i][0], sp[i][1], sp[i][2], sp[i][3]};
                *reinterpret_cast<float4*>(out_sparse + (size_t)t * 4) = spv;
                float2 ivv = {iv0[i], iv1[i]};
                *reinterpret_cast<float2*>(out_idx + (size_t)t * 2) = ivv;
                float4 lvv = {lv[i][0], lv[i][1], lv[i][2], lv[i][3]};
                *reinterpret_cast<float4*>(out_logit + (size_t)t * 4) = lvv;
            }
        }
    }
}

extern "C" void kernel_launch(void* const* d_in, const int* in_sizes, int n_in,
                              void* d_out, int out_size, void* d_ws, size_t ws_size,
                              hipStream_t stream) {
    const float* x      = (const float*)d_in[0];
    const float* gate_w = (const float*)d_in[1];
    const float* gate_b = (const float*)d_in[2];

    const int T = in_sizes[0] / HIDDEN;   // 65536 for B=8, S=8192

    float* out_sparse = (float*)d_out;                       // T*4
    float* out_idx    = out_sparse + (size_t)T * EXPERTS;    // T*2
    float* out_logit  = out_idx    + (size_t)T * 2;          // T*4

    const dim3 block(256);
    const dim3 grid(1024);   // 4096 waves x 4 tokens/iter -> 4 iters/wave
    gating_kernel<<<grid, block, 0, stream>>>(x, gate_w, gate_b,
                                              out_sparse, out_idx, out_logit, T);
}